// Round 11
// baseline (250.542 us; speedup 1.0000x reference)
//
#include <hip/hip_runtime.h>
#include <hip/hip_bf16.h>

#define N_NODES 50000
#define N_EDGES 800000
#define IN_DIM  128
#define IN_CH   64
#define HIDDEN  64
#define OUT_CH  128
#define NUM_CLS 16
#define NUM_G   512
#define NBUK    ((N_NODES + 255) >> 8)    // 196 buckets of 256 dst nodes
#define BCAP    6144                      // mean 4082/bucket -> huge margin
#define EPB_A   4096                      // edges per pass-A block
#define S1BLK   782                       // stage1 blocks in fused dispatch (782*64 >= 50000)

typedef __attribute__((ext_vector_type(8))) short short8;
typedef __attribute__((ext_vector_type(4))) float f32x4;

__device__ inline float bits2f(unsigned short u) {
  unsigned x = (unsigned)u << 16;
  float f;
  __builtin_memcpy(&f, &x, 4);
  return f;
}
__device__ inline unsigned short f2bits(float v) {
  __hip_bfloat16 b = __float2bfloat16(v);   // RNE
  unsigned short s;
  __builtin_memcpy(&s, &b, 2);
  return s;
}
__device__ inline short8 zero8() {
  short8 z;
#pragma unroll
  for (int i = 0; i < 8; ++i) z[i] = 0;
  return z;
}
__device__ inline void acc2(float& a0, float& a1, unsigned v) {
  a0 += bits2f((unsigned short)v);
  a1 += bits2f((unsigned short)(v >> 16));
}
__device__ inline void accu4(float* a, uint4 v) {
  acc2(a[0], a[1], v.x); acc2(a[2], a[3], v.y);
  acc2(a[4], a[5], v.z); acc2(a[6], a[7], v.w);
}

// ============ stage1 body: one wave per 16 rows (R0-proven) ============
__device__ inline void stage1_wave(const float* __restrict__ Ap,
    const short* __restrict__ Wa, const float* __restrict__ bias,
    unsigned short* __restrict__ outp, int rbase, int lane) {
  constexpr int DIN = 128, DOUT = 64, KT = DIN / 32, CT = DOUT / 16;
  const int m = lane & 15;
  const int q = lane >> 4;
  const int row = rbase + m;
  const bool ok = row < N_NODES;

  short8 afr[KT];
#pragma unroll
  for (int kt = 0; kt < KT; ++kt) {
    short8 f = zero8();
    if (ok) {
      const float* ap = Ap + (size_t)row * DIN + kt * 32 + q * 8;
      float4 x0 = *(const float4*)ap;
      float4 x1 = *(const float4*)(ap + 4);
      f[0] = (short)f2bits(x0.x); f[1] = (short)f2bits(x0.y);
      f[2] = (short)f2bits(x0.z); f[3] = (short)f2bits(x0.w);
      f[4] = (short)f2bits(x1.x); f[5] = (short)f2bits(x1.y);
      f[6] = (short)f2bits(x1.z); f[7] = (short)f2bits(x1.w);
    }
    afr[kt] = f;
  }
#pragma unroll
  for (int ct = 0; ct < CT; ++ct) {
    f32x4 c = {0.f, 0.f, 0.f, 0.f};
#pragma unroll
    for (int kt = 0; kt < KT; ++kt) {
      short8 b = *(const short8*)(Wa + ((size_t)(kt * CT + ct) * 64 + lane) * 8);
      c = __builtin_amdgcn_mfma_f32_16x16x32_bf16(afr[kt], b, c, 0, 0, 0);
    }
    float bv = bias[ct * 16 + m];
#pragma unroll
    for (int r = 0; r < 4; ++r) {
      int ro = rbase + q * 4 + r;
      if (ro < N_NODES) outp[(size_t)ro * DOUT + ct * 16 + m] = f2bits(c[r] + bv);
    }
  }
}

// ============ fused gather + dual MFMA, one wave per 16 nodes ============
// Ledger: R9 edge-split ✗; R12 node perm ✗; R13 direct scatter ✗; R16
// 2-wave K-split ✗; R17 src-band sort: FETCH 82->63MB, time flat; R18
// launch_bounds(64,3) alone ✗ (VGPR 60->68 only, time 46->49: the compiler
// does NOT software-pipeline gather iterations regardless of reg headroom).
// Arithmetic: 870 cyc per 2-edge iter == one full miss latency -> depth ~1.
// R19: EXPLICIT ping-pong batch pipeline. Two named reg buffers of 16 uint4
// (EB=8 edges @DIN=64, EB=4 @DIN=128); LOAD(next) issued BEFORE ACC(cur)
// forces counted-vmcnt overlap: ~8 edges in flight under ~512 cyc of VALU.
// All indices compile-time (full unroll, no scratch). Sub-EB tail uses the
// proven 2-edge/1-edge loops.
template <int DIN, int DOUT>
__global__ __launch_bounds__(64, 2) void k_fused(
    const unsigned short* __restrict__ h, const int* __restrict__ esrc,
    const int* __restrict__ off, const short* __restrict__ Wa,
    const short* __restrict__ Wh, const float* __restrict__ bias,
    unsigned short* __restrict__ outp) {
  constexpr int KT = DIN / 32;
  constexpr int CT = DOUT / 16;
  constexpr int EB = (DIN == 64) ? 8 : 4;   // 16 uint4 per buffer either way
  const int lane = threadIdx.x;
  const int m = lane & 15;
  const int q = lane >> 4;
  const int node = blockIdx.x * 16 + m;  // N_NODES == 16*3125: always valid

  float acc[KT][8];
#pragma unroll
  for (int kt = 0; kt < KT; ++kt)
#pragma unroll
    for (int j = 0; j < 8; ++j) acc[kt][j] = 0.f;

  {
    int e = off[node], end = off[node + 1];
    const unsigned short* hq = h + q * 8;

    uint4 bufA[EB][KT], bufB[EB][KT];

    auto LOAD = [&](uint4 (&buf)[EB][KT], int base) {
      int ss[EB];
#pragma unroll
      for (int i = 0; i < EB; ++i) ss[i] = esrc[base + i];
#pragma unroll
      for (int i = 0; i < EB; ++i) {
        const unsigned short* r = hq + (size_t)ss[i] * DIN;
#pragma unroll
        for (int kt = 0; kt < KT; ++kt)
          buf[i][kt] = *(const uint4*)(r + kt * 32);
      }
    };
    auto ACCB = [&](uint4 (&buf)[EB][KT]) {
#pragma unroll
      for (int i = 0; i < EB; ++i)
#pragma unroll
        for (int kt = 0; kt < KT; ++kt)
          accu4(acc[kt], buf[i][kt]);
    };

    if (e + EB <= end) {
      LOAD(bufA, e); e += EB;
      for (; e + 2 * EB <= end; e += 2 * EB) {
        LOAD(bufB, e);          // next batch in flight...
        ACCB(bufA);             // ...while unpacking current (counted vmcnt)
        LOAD(bufA, e + EB);
        ACCB(bufB);
      }
      if (e + EB <= end) {
        LOAD(bufB, e);
        ACCB(bufA);
        ACCB(bufB);
        e += EB;
      } else {
        ACCB(bufA);
      }
    }
    // tail < EB edges: proven 2-edge interleave + single
    for (; e + 2 <= end; e += 2) {
      int s0 = esrc[e], s1 = esrc[e + 1];
      const unsigned short* r0 = hq + (size_t)s0 * DIN;
      const unsigned short* r1 = hq + (size_t)s1 * DIN;
#pragma unroll
      for (int kt = 0; kt < KT; ++kt) {
        uint4 va = *(const uint4*)(r0 + kt * 32);
        uint4 vb = *(const uint4*)(r1 + kt * 32);
        accu4(acc[kt], va);
        accu4(acc[kt], vb);
      }
    }
    if (e < end) {
      const unsigned short* r0 = hq + (size_t)esrc[e] * DIN;
#pragma unroll
      for (int kt = 0; kt < KT; ++kt)
        accu4(acc[kt], *(const uint4*)(r0 + kt * 32));
    }
  }

  short8 afr[KT], hfr[KT];
#pragma unroll
  for (int kt = 0; kt < KT; ++kt) {
    short8 f;
#pragma unroll
    for (int j = 0; j < 8; ++j) f[j] = (short)f2bits(acc[kt][j]);
    afr[kt] = f;
    hfr[kt] = *(const short8*)(h + (size_t)node * DIN + kt * 32 + q * 8);
  }

  const int rbase = blockIdx.x * 16;
#pragma unroll
  for (int ct = 0; ct < CT; ++ct) {
    f32x4 c = {0.f, 0.f, 0.f, 0.f};
#pragma unroll
    for (int kt = 0; kt < KT; ++kt) {
      short8 b = *(const short8*)(Wa + ((size_t)(kt * CT + ct) * 64 + lane) * 8);
      c = __builtin_amdgcn_mfma_f32_16x16x32_bf16(afr[kt], b, c, 0, 0, 0);
      short8 bh = *(const short8*)(Wh + ((size_t)(kt * CT + ct) * 64 + lane) * 8);
      c = __builtin_amdgcn_mfma_f32_16x16x32_bf16(hfr[kt], bh, c, 0, 0, 0);
    }
    float bv = bias[ct * 16 + m];
#pragma unroll
    for (int r = 0; r < 4; ++r) {
      int row = rbase + q * 4 + r;
      outp[(size_t)row * DOUT + ct * 16 + m] = f2bits(fmaxf(c[r] + bv, 0.f));
    }
  }
}

// ============ weight pack helper (flat index over all 7 matrices) ============
template <int DIN, int DOUT>
__device__ inline void pack1(const float* __restrict__ W, short* __restrict__ o,
                             int t) {
  constexpr int CT = DOUT / 16;
  int j = t & 7;
  int lane = (t >> 3) & 63;
  int kc = t >> 9;
  int ct = kc % CT;
  int kt = kc / CT;
  int k = kt * 32 + (lane >> 4) * 8 + j;
  int n = ct * 16 + (lane & 15);
  o[t] = (short)f2bits(W[k * DOUT + n]);
}

struct PackArgs {
  const float *w1, *r1, *o1, *r2, *o2, *r3, *o3;
  short *w1p, *r1p, *o1p, *r2p, *o2p, *r3p, *o3p;
};

__device__ inline void packflat(const PackArgs& a, int t) {
  if      (t < 8192)  pack1<128, 64>(a.w1, a.w1p, t);
  else if (t < 12288) pack1<64, 64>(a.r1, a.r1p, t - 8192);
  else if (t < 16384) pack1<64, 64>(a.o1, a.o1p, t - 12288);
  else if (t < 24576) pack1<64, 128>(a.r2, a.r2p, t - 16384);
  else if (t < 32768) pack1<64, 128>(a.o2, a.o2p, t - 24576);
  else if (t < 49152) pack1<128, 128>(a.r3, a.r3p, t - 32768);
  else if (t < 65536) pack1<128, 128>(a.o3, a.o3p, t - 49152);
}

// ================= bucketed CSR build (pass A) + weight pack =================
// R14: bbuf entry packed to 4B: (src<<8)|(dst&255). src<50000<2^16 -> 24 bits.
__global__ __launch_bounds__(256) void k_bucketA(const int* __restrict__ src,
    const int* __restrict__ dst, int* __restrict__ bcnt,
    unsigned* __restrict__ bbuf, PackArgs pk) {
  __shared__ int hist[NBUK], sbase[NBUK], lcur[NBUK];
  const int t = threadIdx.x;

  // fold weight packing in: 196 blocks x 256 thr = 50176 threads, 65536 items
  {
    int g0 = blockIdx.x * 256 + t;
    packflat(pk, g0);
    packflat(pk, g0 + 50176);
  }

  for (int i = t; i < NBUK; i += 256) { hist[i] = 0; lcur[i] = 0; }
  __syncthreads();
  const int e0 = blockIdx.x * EPB_A;
  int s_[16], d_[16];
  int cnt = 0;
#pragma unroll
  for (int k = 0; k < 16; ++k) {
    int e = e0 + k * 256 + t;
    if (e < N_EDGES) {
      s_[cnt] = src[e]; d_[cnt] = dst[e];
      atomicAdd(&hist[d_[cnt] >> 8], 1);
      cnt++;
    }
  }
  __syncthreads();
  for (int i = t; i < NBUK; i += 256) sbase[i] = atomicAdd(&bcnt[i], hist[i]);
  __syncthreads();
  for (int k = 0; k < cnt; ++k) {
    int b = d_[k] >> 8;
    int pos = sbase[b] + atomicAdd(&lcur[b], 1);
    if (pos < BCAP)
      bbuf[(size_t)b * BCAP + pos] =
          ((unsigned)s_[k] << 8) | ((unsigned)d_[k] & 255u);
  }
}

// ===== R14: bfin + stage1 in ONE dispatch. R17: (node, src-band) sort ======
__global__ __launch_bounds__(256) void k_bfin_s1(const int* __restrict__ bcnt,
    const unsigned* __restrict__ bbuf, int* __restrict__ off,
    int* __restrict__ esrc,
    const float* __restrict__ x, const short* __restrict__ w1p,
    const float* __restrict__ b1, unsigned short* __restrict__ P) {
  if (blockIdx.x >= NBUK) {
    const int bs = blockIdx.x - NBUK;
    const int wave = threadIdx.x >> 6;
    const int lane = threadIdx.x & 63;
    stage1_wave(x, w1p, b1, P, bs * 64 + wave * 16, lane);
    return;
  }

  __shared__ int cnt2[4096];          // 256 nodes x 16 src-bands (src>>12 <= 12)
  __shared__ int s[256];
  __shared__ int bbase_s;
  const int b = blockIdx.x;
  const int t = threadIdx.x;

#pragma unroll
  for (int i = 0; i < 16; ++i) cnt2[t * 16 + i] = 0;

  // bucket-base scan, redundantly per block (196 ints -> trivial)
  int bv0 = (t < NBUK) ? min(bcnt[t], BCAP) : 0;
  s[t] = bv0;
  __syncthreads();
  for (int st = 1; st < 256; st <<= 1) {
    int v = (t >= st) ? s[t - st] : 0;
    __syncthreads();
    s[t] += v;
    __syncthreads();
  }
  if (t == b) bbase_s = s[t] - bv0;                 // exclusive prefix for bucket b
  if (b == 0 && t == NBUK - 1) off[N_NODES] = s[t]; // total edge count
  __syncthreads();
  const int bb = bbase_s;

  // count into (node, band) bins
  const int n = min(bcnt[b], BCAP);
  for (int i = t; i < n; i += 256) {
    unsigned p = bbuf[(size_t)b * BCAP + i];
    int key = (int)(p & 255u) * 16 + (int)((p >> 8) >> 12);
    atomicAdd(&cnt2[key], 1);
  }
  __syncthreads();

  // thread t owns node t: local scan over its 16 bands (sum = degree)
  int run = 0;
#pragma unroll
  for (int i = 0; i < 16; ++i) {
    int tmp = cnt2[t * 16 + i];
    cnt2[t * 16 + i] = run;
    run += tmp;
  }
  const int v0 = run;
  s[t] = v0;
  __syncthreads();
  for (int st = 1; st < 256; st <<= 1) {
    int v = (t >= st) ? s[t - st] : 0;
    __syncthreads();
    s[t] += v;
    __syncthreads();
  }
  const int myoff = bb + s[t] - v0;
  const int node = b * 256 + t;
  if (node < N_NODES) off[node] = myoff;
#pragma unroll
  for (int i = 0; i < 16; ++i) cnt2[t * 16 + i] += myoff;
  __syncthreads();

  // scatter: cnt2 doubles as offset+cursor (atomic return = slot)
  for (int i = t; i < n; i += 256) {
    unsigned p = bbuf[(size_t)b * BCAP + i];
    int srcv = (int)(p >> 8);
    int key = (int)(p & 255u) * 16 + (srcv >> 12);
    int pos = atomicAdd(&cnt2[key], 1);
    esrc[pos] = srcv;
  }
}

// ================= fused pool + head =================
__device__ inline int lbound(const int* __restrict__ a, int n, int v) {
  int lo = 0, hi = n;
  while (lo < hi) {
    int m = (lo + hi) >> 1;
    if (a[m] < v) lo = m + 1; else hi = m;
  }
  return lo;
}

__global__ __launch_bounds__(128) void k_poolhead(const unsigned short* __restrict__ h3,
    const int* __restrict__ batch, const float* __restrict__ lw,
    const float* __restrict__ lb, float* __restrict__ out) {
  __shared__ float sp[128];
  int g = blockIdx.x;
  int t = threadIdx.x;
  int lo = lbound(batch, N_NODES, g);
  int hi = lbound(batch, N_NODES, g + 1);
  float a0 = 0.f, a1 = 0.f, a2 = 0.f, a3 = 0.f;
  int r = lo;
  for (; r + 4 <= hi; r += 4) {
    a0 += bits2f(h3[(size_t)(r + 0) * OUT_CH + t]);
    a1 += bits2f(h3[(size_t)(r + 1) * OUT_CH + t]);
    a2 += bits2f(h3[(size_t)(r + 2) * OUT_CH + t]);
    a3 += bits2f(h3[(size_t)(r + 3) * OUT_CH + t]);
  }
  for (; r < hi; ++r) a0 += bits2f(h3[(size_t)r * OUT_CH + t]);
  float inv = (hi > lo) ? 1.f / (float)(hi - lo) : 0.f;
  sp[t] = ((a0 + a1) + (a2 + a3)) * inv;
  __syncthreads();
  if (t < NUM_CLS) {
    float s = lb[t];
#pragma unroll
    for (int k = 0; k < OUT_CH; ++k) s = fmaf(sp[k], lw[k * NUM_CLS + t], s);
    out[g * NUM_CLS + t] = s;
  }
}

extern "C" void kernel_launch(void* const* d_in, const int* in_sizes, int n_in,
                              void* d_out, int out_size, void* d_ws, size_t ws_size,
                              hipStream_t stream) {
  const float* x      = (const float*)d_in[0];
  const int*   ei     = (const int*)d_in[1];
  const int*   batch  = (const int*)d_in[2];
  const float* w1     = (const float*)d_in[4];
  const float* b1     = (const float*)d_in[5];
  const float* rel1w  = (const float*)d_in[6];
  const float* rel1b  = (const float*)d_in[7];
  const float* root1w = (const float*)d_in[8];
  const float* rel2w  = (const float*)d_in[9];
  const float* rel2b  = (const float*)d_in[10];
  const float* root2w = (const float*)d_in[11];
  const float* rel3w  = (const float*)d_in[12];
  const float* rel3b  = (const float*)d_in[13];
  const float* root3w = (const float*)d_in[14];
  const float* linw   = (const float*)d_in[15];
  const float* linb   = (const float*)d_in[16];
  const int* src = ei;
  const int* dst = ei + N_EDGES;
  float* out = (float*)d_out;

  // ---- workspace layout (bbuf 4B/entry: ~4.8MB smaller than baseline) ----
  unsigned short* P = (unsigned short*)d_ws;            // [N,128] bf16
  unsigned short* Q = P + (size_t)N_NODES * 128;        // [N,128] bf16
  unsigned short* R = Q + (size_t)N_NODES * 128;        // [N,128] bf16
  short* WP = (short*)(R + (size_t)N_NODES * 128);
  short* w1p  = WP;                 // 128x64
  short* r1p  = w1p + 8192;         // 64x64
  short* o1p  = r1p + 4096;         // 64x64
  short* r2p  = o1p + 4096;         // 64x128
  short* o2p  = r2p + 8192;         // 64x128
  short* r3p  = o2p + 8192;         // 128x128
  short* o3p  = r3p + 16384;        // 128x128
  int* off     = (int*)(o3p + 16384);                   // N+1
  int* bcnt    = off + (N_NODES + 1);                   // NBUK
  int* esrc    = bcnt + NBUK + 3;                       // [E]
  unsigned* bbuf = (unsigned*)(esrc + N_EDGES);         // [NBUK*BCAP] packed

  PackArgs pk = {w1, rel1w, root1w, rel2w, root2w, rel3w, root3w,
                 w1p, r1p, o1p, r2p, o2p, r3p, o3p};

  // ---- bucketed CSR build + weight pack; stage1 fused into bfin dispatch ----
  hipMemsetAsync(bcnt, 0, NBUK * sizeof(int), stream);
  k_bucketA<<<(N_EDGES + EPB_A - 1) / EPB_A, 256, 0, stream>>>(src, dst, bcnt,
                                                               bbuf, pk);
  k_bfin_s1<<<NBUK + S1BLK, 256, 0, stream>>>(bcnt, bbuf, off, esrc,
                                              x, w1p, b1, P);

  const int GF = (N_NODES + 15) / 16;     // 3125 blocks, 16 nodes / 1 wave each

  // ---- pipeline ----
  k_fused<64, 64><<<GF, 64, 0, stream>>>(P, esrc, off, r1p, o1p, rel1b, R);
  k_fused<64, 128><<<GF, 64, 0, stream>>>(R, esrc, off, r2p, o2p, rel2b, Q);
  k_fused<128, 128><<<GF, 64, 0, stream>>>(Q, esrc, off, r3p, o3p, rel3b, P);
  k_poolhead<<<NUM_G, 128, 0, stream>>>(P, batch, linw, linb, out);
}

// Round 12
// 239.464 us; speedup vs baseline: 1.0463x; 1.0463x over previous
//
#include <hip/hip_runtime.h>
#include <hip/hip_bf16.h>

#define N_NODES 50000
#define N_EDGES 800000
#define IN_DIM  128
#define IN_CH   64
#define HIDDEN  64
#define OUT_CH  128
#define NUM_CLS 16
#define NUM_G   512
#define NBUK    ((N_NODES + 255) >> 8)    // 196 buckets of 256 dst nodes
#define BCAP    6144                      // mean 4082/bucket -> huge margin
#define EPB_A   4096                      // edges per pass-A block
#define S1BLK   782                       // stage1 blocks in fused dispatch (782*64 >= 50000)

typedef __attribute__((ext_vector_type(8))) short short8;
typedef __attribute__((ext_vector_type(4))) float f32x4;

__device__ inline float bits2f(unsigned short u) {
  unsigned x = (unsigned)u << 16;
  float f;
  __builtin_memcpy(&f, &x, 4);
  return f;
}
__device__ inline unsigned short f2bits(float v) {
  __hip_bfloat16 b = __float2bfloat16(v);   // RNE
  unsigned short s;
  __builtin_memcpy(&s, &b, 2);
  return s;
}
__device__ inline short8 zero8() {
  short8 z;
#pragma unroll
  for (int i = 0; i < 8; ++i) z[i] = 0;
  return z;
}
__device__ inline void acc2(float& a0, float& a1, unsigned v) {
  a0 += bits2f((unsigned short)v);
  a1 += bits2f((unsigned short)(v >> 16));
}
__device__ inline void accu4(float* a, uint4 v) {
  acc2(a[0], a[1], v.x); acc2(a[2], a[3], v.y);
  acc2(a[4], a[5], v.z); acc2(a[6], a[7], v.w);
}

// ============ stage1 body: one wave per 16 rows (R0-proven) ============
__device__ inline void stage1_wave(const float* __restrict__ Ap,
    const short* __restrict__ Wa, const float* __restrict__ bias,
    unsigned short* __restrict__ outp, int rbase, int lane) {
  constexpr int DIN = 128, DOUT = 64, KT = DIN / 32, CT = DOUT / 16;
  const int m = lane & 15;
  const int q = lane >> 4;
  const int row = rbase + m;
  const bool ok = row < N_NODES;

  short8 afr[KT];
#pragma unroll
  for (int kt = 0; kt < KT; ++kt) {
    short8 f = zero8();
    if (ok) {
      const float* ap = Ap + (size_t)row * DIN + kt * 32 + q * 8;
      float4 x0 = *(const float4*)ap;
      float4 x1 = *(const float4*)(ap + 4);
      f[0] = (short)f2bits(x0.x); f[1] = (short)f2bits(x0.y);
      f[2] = (short)f2bits(x0.z); f[3] = (short)f2bits(x0.w);
      f[4] = (short)f2bits(x1.x); f[5] = (short)f2bits(x1.y);
      f[6] = (short)f2bits(x1.z); f[7] = (short)f2bits(x1.w);
    }
    afr[kt] = f;
  }
#pragma unroll
  for (int ct = 0; ct < CT; ++ct) {
    f32x4 c = {0.f, 0.f, 0.f, 0.f};
#pragma unroll
    for (int kt = 0; kt < KT; ++kt) {
      short8 b = *(const short8*)(Wa + ((size_t)(kt * CT + ct) * 64 + lane) * 8);
      c = __builtin_amdgcn_mfma_f32_16x16x32_bf16(afr[kt], b, c, 0, 0, 0);
    }
    float bv = bias[ct * 16 + m];
#pragma unroll
    for (int r = 0; r < 4; ++r) {
      int ro = rbase + q * 4 + r;
      if (ro < N_NODES) outp[(size_t)ro * DOUT + ct * 16 + m] = f2bits(c[r] + bv);
    }
  }
}

// ============ fused gather + dual MFMA, one wave per 16 nodes ============
// FINAL form (R20): the R8/R14/R17-proven loop. The gather is a dependent
// two-level chain (esrc -> row); CDNA's ordered vmcnt means consuming a
// later-issued index load drains all earlier row loads, so no source-level
// pipeline exists. Proven-dead axes: R9 edge-split, R10/R15 wider ILP,
// R12 node perm, R16 2-wave K-split, R18 reg-budget lift, R19 explicit
// ping-pong (spilled, 15% occ, +3us). ~435 cyc/edge is this structure's
// wall; leave this loop alone.
template <int DIN, int DOUT>
__global__ __launch_bounds__(64) void k_fused(
    const unsigned short* __restrict__ h, const int* __restrict__ esrc,
    const int* __restrict__ off, const short* __restrict__ Wa,
    const short* __restrict__ Wh, const float* __restrict__ bias,
    unsigned short* __restrict__ outp) {
  constexpr int KT = DIN / 32;
  constexpr int CT = DOUT / 16;
  const int lane = threadIdx.x;
  const int m = lane & 15;
  const int q = lane >> 4;
  const int node = blockIdx.x * 16 + m;  // N_NODES == 16*3125: always valid

  float acc[KT][8];
#pragma unroll
  for (int kt = 0; kt < KT; ++kt)
#pragma unroll
    for (int j = 0; j < 8; ++j) acc[kt][j] = 0.f;

  {
    int e = off[node], end = off[node + 1];
    const unsigned short* hq = h + q * 8;
    for (; e + 2 <= end; e += 2) {
      int s0 = esrc[e], s1 = esrc[e + 1];
      const unsigned short* r0 = hq + (size_t)s0 * DIN;
      const unsigned short* r1 = hq + (size_t)s1 * DIN;
#pragma unroll
      for (int kt = 0; kt < KT; ++kt) {
        uint4 va = *(const uint4*)(r0 + kt * 32);
        uint4 vb = *(const uint4*)(r1 + kt * 32);
        accu4(acc[kt], va);
        accu4(acc[kt], vb);
      }
    }
    if (e < end) {
      const unsigned short* r0 = hq + (size_t)esrc[e] * DIN;
#pragma unroll
      for (int kt = 0; kt < KT; ++kt)
        accu4(acc[kt], *(const uint4*)(r0 + kt * 32));
    }
  }

  short8 afr[KT], hfr[KT];
#pragma unroll
  for (int kt = 0; kt < KT; ++kt) {
    short8 f;
#pragma unroll
    for (int j = 0; j < 8; ++j) f[j] = (short)f2bits(acc[kt][j]);
    afr[kt] = f;
    hfr[kt] = *(const short8*)(h + (size_t)node * DIN + kt * 32 + q * 8);
  }

  const int rbase = blockIdx.x * 16;
#pragma unroll
  for (int ct = 0; ct < CT; ++ct) {
    f32x4 c = {0.f, 0.f, 0.f, 0.f};
#pragma unroll
    for (int kt = 0; kt < KT; ++kt) {
      short8 b = *(const short8*)(Wa + ((size_t)(kt * CT + ct) * 64 + lane) * 8);
      c = __builtin_amdgcn_mfma_f32_16x16x32_bf16(afr[kt], b, c, 0, 0, 0);
      short8 bh = *(const short8*)(Wh + ((size_t)(kt * CT + ct) * 64 + lane) * 8);
      c = __builtin_amdgcn_mfma_f32_16x16x32_bf16(hfr[kt], bh, c, 0, 0, 0);
    }
    float bv = bias[ct * 16 + m];
#pragma unroll
    for (int r = 0; r < 4; ++r) {
      int row = rbase + q * 4 + r;
      outp[(size_t)row * DOUT + ct * 16 + m] = f2bits(fmaxf(c[r] + bv, 0.f));
    }
  }
}

// ============ weight pack helper (flat index over all 7 matrices) ============
template <int DIN, int DOUT>
__device__ inline void pack1(const float* __restrict__ W, short* __restrict__ o,
                             int t) {
  constexpr int CT = DOUT / 16;
  int j = t & 7;
  int lane = (t >> 3) & 63;
  int kc = t >> 9;
  int ct = kc % CT;
  int kt = kc / CT;
  int k = kt * 32 + (lane >> 4) * 8 + j;
  int n = ct * 16 + (lane & 15);
  o[t] = (short)f2bits(W[k * DOUT + n]);
}

struct PackArgs {
  const float *w1, *r1, *o1, *r2, *o2, *r3, *o3;
  short *w1p, *r1p, *o1p, *r2p, *o2p, *r3p, *o3p;
};

__device__ inline void packflat(const PackArgs& a, int t) {
  if      (t < 8192)  pack1<128, 64>(a.w1, a.w1p, t);
  else if (t < 12288) pack1<64, 64>(a.r1, a.r1p, t - 8192);
  else if (t < 16384) pack1<64, 64>(a.o1, a.o1p, t - 12288);
  else if (t < 24576) pack1<64, 128>(a.r2, a.r2p, t - 16384);
  else if (t < 32768) pack1<64, 128>(a.o2, a.o2p, t - 24576);
  else if (t < 49152) pack1<128, 128>(a.r3, a.r3p, t - 32768);
  else if (t < 65536) pack1<128, 128>(a.o3, a.o3p, t - 49152);
}

// ================= bucketed CSR build (pass A) + weight pack =================
// R20: per-block LDS counting-sort by bucket BEFORE writing bbuf. The old
// direct scatter sprayed 4B entries randomly across the 4.7MB bbuf range;
// consecutive slots of one bucket are filled by different blocks/XCDs at
// different times -> 64B-line write amplification (R13's pathology, ~50MB).
// Sorted staging writes each bucket's ~21 entries as a contiguous run.
// Staged word carries bucket id in bits 24..31; MASKED off before bbuf
// write, so bbuf content is bit-identical to R14 and k_bfin_s1 is unchanged.
__global__ __launch_bounds__(256) void k_bucketA(const int* __restrict__ src,
    const int* __restrict__ dst, int* __restrict__ bcnt,
    unsigned* __restrict__ bbuf, PackArgs pk) {
  __shared__ int hist[NBUK], sbase[NBUK], lcur[NBUK], lstart[NBUK];
  __shared__ int sc[256];
  __shared__ unsigned stage[EPB_A];
  __shared__ int s_total;
  const int t = threadIdx.x;

  // fold weight packing in: 196 blocks x 256 thr = 50176 threads, 65536 items
  {
    int g0 = blockIdx.x * 256 + t;
    packflat(pk, g0);
    packflat(pk, g0 + 50176);
  }

  for (int i = t; i < NBUK; i += 256) { hist[i] = 0; lcur[i] = 0; }
  __syncthreads();
  const int e0 = blockIdx.x * EPB_A;
  unsigned p_[16];
  int b_[16];
  int cnt = 0;
#pragma unroll
  for (int k = 0; k < 16; ++k) {
    int e = e0 + k * 256 + t;
    if (e < N_EDGES) {
      int sv = src[e], dv = dst[e];
      int bb = dv >> 8;
      p_[cnt] = ((unsigned)bb << 24) | ((unsigned)sv << 8) | ((unsigned)dv & 255u);
      b_[cnt] = bb;
      atomicAdd(&hist[bb], 1);
      cnt++;
    }
  }
  __syncthreads();
  // global base per bucket (cross-block order arbitrary, as before)
  for (int i = t; i < NBUK; i += 256) sbase[i] = atomicAdd(&bcnt[i], hist[i]);
  // local exclusive scan of hist -> lstart; total edges this block
  int hv = (t < NBUK) ? hist[t] : 0;
  sc[t] = hv;
  __syncthreads();
  for (int st = 1; st < 256; st <<= 1) {
    int v = (t >= st) ? sc[t - st] : 0;
    __syncthreads();
    sc[t] += v;
    __syncthreads();
  }
  if (t < NBUK) lstart[t] = sc[t] - hv;
  if (t == 255) s_total = sc[255];
  __syncthreads();
  // stage entries sorted by bucket (LDS only)
  for (int k = 0; k < cnt; ++k) {
    int bb = b_[k];
    int r = atomicAdd(&lcur[bb], 1);
    stage[lstart[bb] + r] = p_[k];
  }
  __syncthreads();
  // contiguous write-out: consecutive threads hit consecutive sorted slots
  const int total = s_total;
  for (int j = t; j < total; j += 256) {
    unsigned v = stage[j];
    int bb = (int)(v >> 24);
    int gpos = sbase[bb] + (j - lstart[bb]);
    if (gpos < BCAP) bbuf[(size_t)bb * BCAP + gpos] = v & 0x00FFFFFFu;
  }
}

// ===== R14: bfin + stage1 in ONE dispatch. R17: (node, src-band) sort ======
__global__ __launch_bounds__(256) void k_bfin_s1(const int* __restrict__ bcnt,
    const unsigned* __restrict__ bbuf, int* __restrict__ off,
    int* __restrict__ esrc,
    const float* __restrict__ x, const short* __restrict__ w1p,
    const float* __restrict__ b1, unsigned short* __restrict__ P) {
  if (blockIdx.x >= NBUK) {
    const int bs = blockIdx.x - NBUK;
    const int wave = threadIdx.x >> 6;
    const int lane = threadIdx.x & 63;
    stage1_wave(x, w1p, b1, P, bs * 64 + wave * 16, lane);
    return;
  }

  __shared__ int cnt2[4096];          // 256 nodes x 16 src-bands (src>>12 <= 12)
  __shared__ int s[256];
  __shared__ int bbase_s;
  const int b = blockIdx.x;
  const int t = threadIdx.x;

#pragma unroll
  for (int i = 0; i < 16; ++i) cnt2[t * 16 + i] = 0;

  // bucket-base scan, redundantly per block (196 ints -> trivial)
  int bv0 = (t < NBUK) ? min(bcnt[t], BCAP) : 0;
  s[t] = bv0;
  __syncthreads();
  for (int st = 1; st < 256; st <<= 1) {
    int v = (t >= st) ? s[t - st] : 0;
    __syncthreads();
    s[t] += v;
    __syncthreads();
  }
  if (t == b) bbase_s = s[t] - bv0;                 // exclusive prefix for bucket b
  if (b == 0 && t == NBUK - 1) off[N_NODES] = s[t]; // total edge count
  __syncthreads();
  const int bb = bbase_s;

  // count into (node, band) bins
  const int n = min(bcnt[b], BCAP);
  for (int i = t; i < n; i += 256) {
    unsigned p = bbuf[(size_t)b * BCAP + i];
    int key = (int)(p & 255u) * 16 + (int)((p >> 8) >> 12);
    atomicAdd(&cnt2[key], 1);
  }
  __syncthreads();

  // thread t owns node t: local scan over its 16 bands (sum = degree)
  int run = 0;
#pragma unroll
  for (int i = 0; i < 16; ++i) {
    int tmp = cnt2[t * 16 + i];
    cnt2[t * 16 + i] = run;
    run += tmp;
  }
  const int v0 = run;
  s[t] = v0;
  __syncthreads();
  for (int st = 1; st < 256; st <<= 1) {
    int v = (t >= st) ? s[t - st] : 0;
    __syncthreads();
    s[t] += v;
    __syncthreads();
  }
  const int myoff = bb + s[t] - v0;
  const int node = b * 256 + t;
  if (node < N_NODES) off[node] = myoff;
#pragma unroll
  for (int i = 0; i < 16; ++i) cnt2[t * 16 + i] += myoff;
  __syncthreads();

  // scatter: cnt2 doubles as offset+cursor (atomic return = slot)
  for (int i = t; i < n; i += 256) {
    unsigned p = bbuf[(size_t)b * BCAP + i];
    int srcv = (int)(p >> 8);
    int key = (int)(p & 255u) * 16 + (srcv >> 12);
    int pos = atomicAdd(&cnt2[key], 1);
    esrc[pos] = srcv;
  }
}

// ================= fused pool + head =================
__device__ inline int lbound(const int* __restrict__ a, int n, int v) {
  int lo = 0, hi = n;
  while (lo < hi) {
    int m = (lo + hi) >> 1;
    if (a[m] < v) lo = m + 1; else hi = m;
  }
  return lo;
}

__global__ __launch_bounds__(128) void k_poolhead(const unsigned short* __restrict__ h3,
    const int* __restrict__ batch, const float* __restrict__ lw,
    const float* __restrict__ lb, float* __restrict__ out) {
  __shared__ float sp[128];
  int g = blockIdx.x;
  int t = threadIdx.x;
  int lo = lbound(batch, N_NODES, g);
  int hi = lbound(batch, N_NODES, g + 1);
  float a0 = 0.f, a1 = 0.f, a2 = 0.f, a3 = 0.f;
  int r = lo;
  for (; r + 4 <= hi; r += 4) {
    a0 += bits2f(h3[(size_t)(r + 0) * OUT_CH + t]);
    a1 += bits2f(h3[(size_t)(r + 1) * OUT_CH + t]);
    a2 += bits2f(h3[(size_t)(r + 2) * OUT_CH + t]);
    a3 += bits2f(h3[(size_t)(r + 3) * OUT_CH + t]);
  }
  for (; r < hi; ++r) a0 += bits2f(h3[(size_t)r * OUT_CH + t]);
  float inv = (hi > lo) ? 1.f / (float)(hi - lo) : 0.f;
  sp[t] = ((a0 + a1) + (a2 + a3)) * inv;
  __syncthreads();
  if (t < NUM_CLS) {
    float s = lb[t];
#pragma unroll
    for (int k = 0; k < OUT_CH; ++k) s = fmaf(sp[k], lw[k * NUM_CLS + t], s);
    out[g * NUM_CLS + t] = s;
  }
}

extern "C" void kernel_launch(void* const* d_in, const int* in_sizes, int n_in,
                              void* d_out, int out_size, void* d_ws, size_t ws_size,
                              hipStream_t stream) {
  const float* x      = (const float*)d_in[0];
  const int*   ei     = (const int*)d_in[1];
  const int*   batch  = (const int*)d_in[2];
  const float* w1     = (const float*)d_in[4];
  const float* b1     = (const float*)d_in[5];
  const float* rel1w  = (const float*)d_in[6];
  const float* rel1b  = (const float*)d_in[7];
  const float* root1w = (const float*)d_in[8];
  const float* rel2w  = (const float*)d_in[9];
  const float* rel2b  = (const float*)d_in[10];
  const float* root2w = (const float*)d_in[11];
  const float* rel3w  = (const float*)d_in[12];
  const float* rel3b  = (const float*)d_in[13];
  const float* root3w = (const float*)d_in[14];
  const float* linw   = (const float*)d_in[15];
  const float* linb   = (const float*)d_in[16];
  const int* src = ei;
  const int* dst = ei + N_EDGES;
  float* out = (float*)d_out;

  // ---- workspace layout (bbuf 4B/entry: ~4.8MB smaller than baseline) ----
  unsigned short* P = (unsigned short*)d_ws;            // [N,128] bf16
  unsigned short* Q = P + (size_t)N_NODES * 128;        // [N,128] bf16
  unsigned short* R = Q + (size_t)N_NODES * 128;        // [N,128] bf16
  short* WP = (short*)(R + (size_t)N_NODES * 128);
  short* w1p  = WP;                 // 128x64
  short* r1p  = w1p + 8192;         // 64x64
  short* o1p  = r1p + 4096;         // 64x64
  short* r2p  = o1p + 4096;         // 64x128
  short* o2p  = r2p + 8192;         // 64x128
  short* r3p  = o2p + 8192;         // 128x128
  short* o3p  = r3p + 16384;        // 128x128
  int* off     = (int*)(o3p + 16384);                   // N+1
  int* bcnt    = off + (N_NODES + 1);                   // NBUK
  int* esrc    = bcnt + NBUK + 3;                       // [E]
  unsigned* bbuf = (unsigned*)(esrc + N_EDGES);         // [NBUK*BCAP] packed

  PackArgs pk = {w1, rel1w, root1w, rel2w, root2w, rel3w, root3w,
                 w1p, r1p, o1p, r2p, o2p, r3p, o3p};

  // ---- bucketed CSR build + weight pack; stage1 fused into bfin dispatch ----
  hipMemsetAsync(bcnt, 0, NBUK * sizeof(int), stream);
  k_bucketA<<<(N_EDGES + EPB_A - 1) / EPB_A, 256, 0, stream>>>(src, dst, bcnt,
                                                               bbuf, pk);
  k_bfin_s1<<<NBUK + S1BLK, 256, 0, stream>>>(bcnt, bbuf, off, esrc,
                                              x, w1p, b1, P);

  const int GF = (N_NODES + 15) / 16;     // 3125 blocks, 16 nodes / 1 wave each

  // ---- pipeline ----
  k_fused<64, 64><<<GF, 64, 0, stream>>>(P, esrc, off, r1p, o1p, rel1b, R);
  k_fused<64, 128><<<GF, 64, 0, stream>>>(R, esrc, off, r2p, o2p, rel2b, Q);
  k_fused<128, 128><<<GF, 64, 0, stream>>>(Q, esrc, off, r3p, o3p, rel3b, P);
  k_poolhead<<<NUM_G, 128, 0, stream>>>(P, batch, linw, linb, out);
}

// Round 13
// 231.079 us; speedup vs baseline: 1.0842x; 1.0363x over previous
//
#include <hip/hip_runtime.h>
#include <hip/hip_bf16.h>

#define N_NODES 50000
#define N_EDGES 800000
#define IN_DIM  128
#define IN_CH   64
#define HIDDEN  64
#define OUT_CH  128
#define NUM_CLS 16
#define NUM_G   512
#define NBUK    ((N_NODES + 255) >> 8)    // 196 buckets of 256 dst nodes
#define BCAP    6144                      // mean 4082/bucket -> huge margin
#define EPB_A   4096                      // edges per pass-A block
#define S1BLK   782                       // stage1 blocks in fused dispatch (782*64 >= 50000)

typedef __attribute__((ext_vector_type(8))) short short8;
typedef __attribute__((ext_vector_type(4))) float f32x4;

__device__ inline float bits2f(unsigned short u) {
  unsigned x = (unsigned)u << 16;
  float f;
  __builtin_memcpy(&f, &x, 4);
  return f;
}
__device__ inline unsigned short f2bits(float v) {
  __hip_bfloat16 b = __float2bfloat16(v);   // RNE
  unsigned short s;
  __builtin_memcpy(&s, &b, 2);
  return s;
}
__device__ inline short8 zero8() {
  short8 z;
#pragma unroll
  for (int i = 0; i < 8; ++i) z[i] = 0;
  return z;
}
__device__ inline void acc2(float& a0, float& a1, unsigned v) {
  a0 += bits2f((unsigned short)v);
  a1 += bits2f((unsigned short)(v >> 16));
}
__device__ inline void accu4(float* a, uint4 v) {
  acc2(a[0], a[1], v.x); acc2(a[2], a[3], v.y);
  acc2(a[4], a[5], v.z); acc2(a[6], a[7], v.w);
}

// ============ stage1 body: one wave per 16 rows (R0-proven) ============
__device__ inline void stage1_wave(const float* __restrict__ Ap,
    const short* __restrict__ Wa, const float* __restrict__ bias,
    unsigned short* __restrict__ outp, int rbase, int lane) {
  constexpr int DIN = 128, DOUT = 64, KT = DIN / 32, CT = DOUT / 16;
  const int m = lane & 15;
  const int q = lane >> 4;
  const int row = rbase + m;
  const bool ok = row < N_NODES;

  short8 afr[KT];
#pragma unroll
  for (int kt = 0; kt < KT; ++kt) {
    short8 f = zero8();
    if (ok) {
      const float* ap = Ap + (size_t)row * DIN + kt * 32 + q * 8;
      float4 x0 = *(const float4*)ap;
      float4 x1 = *(const float4*)(ap + 4);
      f[0] = (short)f2bits(x0.x); f[1] = (short)f2bits(x0.y);
      f[2] = (short)f2bits(x0.z); f[3] = (short)f2bits(x0.w);
      f[4] = (short)f2bits(x1.x); f[5] = (short)f2bits(x1.y);
      f[6] = (short)f2bits(x1.z); f[7] = (short)f2bits(x1.w);
    }
    afr[kt] = f;
  }
#pragma unroll
  for (int ct = 0; ct < CT; ++ct) {
    f32x4 c = {0.f, 0.f, 0.f, 0.f};
#pragma unroll
    for (int kt = 0; kt < KT; ++kt) {
      short8 b = *(const short8*)(Wa + ((size_t)(kt * CT + ct) * 64 + lane) * 8);
      c = __builtin_amdgcn_mfma_f32_16x16x32_bf16(afr[kt], b, c, 0, 0, 0);
    }
    float bv = bias[ct * 16 + m];
#pragma unroll
    for (int r = 0; r < 4; ++r) {
      int ro = rbase + q * 4 + r;
      if (ro < N_NODES) outp[(size_t)ro * DOUT + ct * 16 + m] = f2bits(c[r] + bv);
    }
  }
}

// ============ fused gather + dual MFMA, one wave per 16 nodes ============
// Gather loop = FINAL R8/R14/R17-proven form (dead axes: R9 edge-split,
// R10/R15 wider ILP, R12 node perm, R16 K-split, R18 reg lift, R19
// ping-pong; ~435 cyc/edge dependent-chain wall). R21: POOL flag -- layer 3
// skips the 12.5MB h3 write; epilogue stages the 16x128 tile in LDS
// (bf16-rounded, matching old numerics), segment-reduces rows by graph
// (batch sorted: 1-2 graphs per 16-node window) and atomicAdds per-
// (graph,channel) sums into pooled[512][128]. ~470K atomics over 65K
// addresses (~7/addr, low-contention regime). Kills poolhead's 12.8MB
// re-read + dispatch.
template <int DIN, int DOUT, bool POOL>
__global__ __launch_bounds__(64) void k_fused(
    const unsigned short* __restrict__ h, const int* __restrict__ esrc,
    const int* __restrict__ off, const short* __restrict__ Wa,
    const short* __restrict__ Wh, const float* __restrict__ bias,
    unsigned short* __restrict__ outp, const int* __restrict__ batch,
    float* __restrict__ pooled) {
  constexpr int KT = DIN / 32;
  constexpr int CT = DOUT / 16;
  const int lane = threadIdx.x;
  const int m = lane & 15;
  const int q = lane >> 4;
  const int node = blockIdx.x * 16 + m;  // N_NODES == 16*3125: always valid

  float acc[KT][8];
#pragma unroll
  for (int kt = 0; kt < KT; ++kt)
#pragma unroll
    for (int j = 0; j < 8; ++j) acc[kt][j] = 0.f;

  {
    int e = off[node], end = off[node + 1];
    const unsigned short* hq = h + q * 8;
    for (; e + 2 <= end; e += 2) {
      int s0 = esrc[e], s1 = esrc[e + 1];
      const unsigned short* r0 = hq + (size_t)s0 * DIN;
      const unsigned short* r1 = hq + (size_t)s1 * DIN;
#pragma unroll
      for (int kt = 0; kt < KT; ++kt) {
        uint4 va = *(const uint4*)(r0 + kt * 32);
        uint4 vb = *(const uint4*)(r1 + kt * 32);
        accu4(acc[kt], va);
        accu4(acc[kt], vb);
      }
    }
    if (e < end) {
      const unsigned short* r0 = hq + (size_t)esrc[e] * DIN;
#pragma unroll
      for (int kt = 0; kt < KT; ++kt)
        accu4(acc[kt], *(const uint4*)(r0 + kt * 32));
    }
  }

  short8 afr[KT], hfr[KT];
#pragma unroll
  for (int kt = 0; kt < KT; ++kt) {
    short8 f;
#pragma unroll
    for (int j = 0; j < 8; ++j) f[j] = (short)f2bits(acc[kt][j]);
    afr[kt] = f;
    hfr[kt] = *(const short8*)(h + (size_t)node * DIN + kt * 32 + q * 8);
  }

  const int rbase = blockIdx.x * 16;

  if constexpr (!POOL) {
#pragma unroll
    for (int ct = 0; ct < CT; ++ct) {
      f32x4 c = {0.f, 0.f, 0.f, 0.f};
#pragma unroll
      for (int kt = 0; kt < KT; ++kt) {
        short8 b = *(const short8*)(Wa + ((size_t)(kt * CT + ct) * 64 + lane) * 8);
        c = __builtin_amdgcn_mfma_f32_16x16x32_bf16(afr[kt], b, c, 0, 0, 0);
        short8 bh = *(const short8*)(Wh + ((size_t)(kt * CT + ct) * 64 + lane) * 8);
        c = __builtin_amdgcn_mfma_f32_16x16x32_bf16(hfr[kt], bh, c, 0, 0, 0);
      }
      float bv = bias[ct * 16 + m];
#pragma unroll
      for (int r = 0; r < 4; ++r) {
        int row = rbase + q * 4 + r;
        outp[(size_t)row * DOUT + ct * 16 + m] = f2bits(fmaxf(c[r] + bv, 0.f));
      }
    }
  } else {
    __shared__ float smem[16][DOUT];
    __shared__ int bsm[16];
    if (lane < 16) bsm[lane] = batch[rbase + lane];
#pragma unroll
    for (int ct = 0; ct < CT; ++ct) {
      f32x4 c = {0.f, 0.f, 0.f, 0.f};
#pragma unroll
      for (int kt = 0; kt < KT; ++kt) {
        short8 b = *(const short8*)(Wa + ((size_t)(kt * CT + ct) * 64 + lane) * 8);
        c = __builtin_amdgcn_mfma_f32_16x16x32_bf16(afr[kt], b, c, 0, 0, 0);
        short8 bh = *(const short8*)(Wh + ((size_t)(kt * CT + ct) * 64 + lane) * 8);
        c = __builtin_amdgcn_mfma_f32_16x16x32_bf16(hfr[kt], bh, c, 0, 0, 0);
      }
      float bv = bias[ct * 16 + m];
#pragma unroll
      for (int r = 0; r < 4; ++r) {
        // bf16-round to match the old h3 write exactly, then pool in f32
        smem[q * 4 + r][ct * 16 + m] =
            bits2f(f2bits(fmaxf(c[r] + bv, 0.f)));
      }
    }
    __syncthreads();
    // segment-reduce 16 rows by graph; 2 channels per thread
#pragma unroll
    for (int cc = 0; cc < DOUT / 64; ++cc) {
      const int ch = cc * 64 + lane;
      int g = bsm[0];
      float s = 0.f;
#pragma unroll
      for (int r2 = 0; r2 < 16; ++r2) {
        int gr = bsm[r2];
        if (gr != g) {
          atomicAdd(&pooled[(size_t)g * DOUT + ch], s);
          g = gr;
          s = 0.f;
        }
        s += smem[r2][ch];
      }
      atomicAdd(&pooled[(size_t)g * DOUT + ch], s);
    }
  }
}

// ============ weight pack helper (flat index over all 7 matrices) ============
template <int DIN, int DOUT>
__device__ inline void pack1(const float* __restrict__ W, short* __restrict__ o,
                             int t) {
  constexpr int CT = DOUT / 16;
  int j = t & 7;
  int lane = (t >> 3) & 63;
  int kc = t >> 9;
  int ct = kc % CT;
  int kt = kc / CT;
  int k = kt * 32 + (lane >> 4) * 8 + j;
  int n = ct * 16 + (lane & 15);
  o[t] = (short)f2bits(W[k * DOUT + n]);
}

struct PackArgs {
  const float *w1, *r1, *o1, *r2, *o2, *r3, *o3;
  short *w1p, *r1p, *o1p, *r2p, *o2p, *r3p, *o3p;
};

__device__ inline void packflat(const PackArgs& a, int t) {
  if      (t < 8192)  pack1<128, 64>(a.w1, a.w1p, t);
  else if (t < 12288) pack1<64, 64>(a.r1, a.r1p, t - 8192);
  else if (t < 16384) pack1<64, 64>(a.o1, a.o1p, t - 12288);
  else if (t < 24576) pack1<64, 128>(a.r2, a.r2p, t - 16384);
  else if (t < 32768) pack1<64, 128>(a.o2, a.o2p, t - 24576);
  else if (t < 49152) pack1<128, 128>(a.r3, a.r3p, t - 32768);
  else if (t < 65536) pack1<128, 128>(a.o3, a.o3p, t - 49152);
}

// ================= bucketed CSR build (pass A) + weight pack =================
// R20: per-block LDS counting-sort by bucket before writing bbuf (kills the
// cross-XCD 64B-line write amplification of the old direct scatter).
// R21: also zeroes pooled[] (stream-ordered well before layer 3 uses it).
__global__ __launch_bounds__(256) void k_bucketA(const int* __restrict__ src,
    const int* __restrict__ dst, int* __restrict__ bcnt,
    unsigned* __restrict__ bbuf, float* __restrict__ pooled, PackArgs pk) {
  __shared__ int hist[NBUK], sbase[NBUK], lcur[NBUK], lstart[NBUK];
  __shared__ int sc[256];
  __shared__ unsigned stage[EPB_A];
  __shared__ int s_total;
  const int t = threadIdx.x;

  // fold weight packing + pooled zeroing in (196 blocks x 256 thr)
  {
    int g0 = blockIdx.x * 256 + t;
    packflat(pk, g0);
    packflat(pk, g0 + 50176);
    if (g0 < NUM_G * OUT_CH) pooled[g0] = 0.f;
    int g1 = g0 + 50176;
    if (g1 < NUM_G * OUT_CH) pooled[g1] = 0.f;
  }

  for (int i = t; i < NBUK; i += 256) { hist[i] = 0; lcur[i] = 0; }
  __syncthreads();
  const int e0 = blockIdx.x * EPB_A;
  unsigned p_[16];
  int b_[16];
  int cnt = 0;
#pragma unroll
  for (int k = 0; k < 16; ++k) {
    int e = e0 + k * 256 + t;
    if (e < N_EDGES) {
      int sv = src[e], dv = dst[e];
      int bb = dv >> 8;
      p_[cnt] = ((unsigned)bb << 24) | ((unsigned)sv << 8) | ((unsigned)dv & 255u);
      b_[cnt] = bb;
      atomicAdd(&hist[bb], 1);
      cnt++;
    }
  }
  __syncthreads();
  // global base per bucket (cross-block order arbitrary, as before)
  for (int i = t; i < NBUK; i += 256) sbase[i] = atomicAdd(&bcnt[i], hist[i]);
  // local exclusive scan of hist -> lstart; total edges this block
  int hv = (t < NBUK) ? hist[t] : 0;
  sc[t] = hv;
  __syncthreads();
  for (int st = 1; st < 256; st <<= 1) {
    int v = (t >= st) ? sc[t - st] : 0;
    __syncthreads();
    sc[t] += v;
    __syncthreads();
  }
  if (t < NBUK) lstart[t] = sc[t] - hv;
  if (t == 255) s_total = sc[255];
  __syncthreads();
  // stage entries sorted by bucket (LDS only)
  for (int k = 0; k < cnt; ++k) {
    int bb = b_[k];
    int r = atomicAdd(&lcur[bb], 1);
    stage[lstart[bb] + r] = p_[k];
  }
  __syncthreads();
  // contiguous write-out: consecutive threads hit consecutive sorted slots
  const int total = s_total;
  for (int j = t; j < total; j += 256) {
    unsigned v = stage[j];
    int bb = (int)(v >> 24);
    int gpos = sbase[bb] + (j - lstart[bb]);
    if (gpos < BCAP) bbuf[(size_t)bb * BCAP + gpos] = v & 0x00FFFFFFu;
  }
}

// ===== R14: bfin + stage1 in ONE dispatch. R17: (node, src-band) sort ======
__global__ __launch_bounds__(256) void k_bfin_s1(const int* __restrict__ bcnt,
    const unsigned* __restrict__ bbuf, int* __restrict__ off,
    int* __restrict__ esrc,
    const float* __restrict__ x, const short* __restrict__ w1p,
    const float* __restrict__ b1, unsigned short* __restrict__ P) {
  if (blockIdx.x >= NBUK) {
    const int bs = blockIdx.x - NBUK;
    const int wave = threadIdx.x >> 6;
    const int lane = threadIdx.x & 63;
    stage1_wave(x, w1p, b1, P, bs * 64 + wave * 16, lane);
    return;
  }

  __shared__ int cnt2[4096];          // 256 nodes x 16 src-bands (src>>12 <= 12)
  __shared__ int s[256];
  __shared__ int bbase_s;
  const int b = blockIdx.x;
  const int t = threadIdx.x;

#pragma unroll
  for (int i = 0; i < 16; ++i) cnt2[t * 16 + i] = 0;

  // bucket-base scan, redundantly per block (196 ints -> trivial)
  int bv0 = (t < NBUK) ? min(bcnt[t], BCAP) : 0;
  s[t] = bv0;
  __syncthreads();
  for (int st = 1; st < 256; st <<= 1) {
    int v = (t >= st) ? s[t - st] : 0;
    __syncthreads();
    s[t] += v;
    __syncthreads();
  }
  if (t == b) bbase_s = s[t] - bv0;                 // exclusive prefix for bucket b
  if (b == 0 && t == NBUK - 1) off[N_NODES] = s[t]; // total edge count
  __syncthreads();
  const int bb = bbase_s;

  // count into (node, band) bins
  const int n = min(bcnt[b], BCAP);
  for (int i = t; i < n; i += 256) {
    unsigned p = bbuf[(size_t)b * BCAP + i];
    int key = (int)(p & 255u) * 16 + (int)((p >> 8) >> 12);
    atomicAdd(&cnt2[key], 1);
  }
  __syncthreads();

  // thread t owns node t: local scan over its 16 bands (sum = degree)
  int run = 0;
#pragma unroll
  for (int i = 0; i < 16; ++i) {
    int tmp = cnt2[t * 16 + i];
    cnt2[t * 16 + i] = run;
    run += tmp;
  }
  const int v0 = run;
  s[t] = v0;
  __syncthreads();
  for (int st = 1; st < 256; st <<= 1) {
    int v = (t >= st) ? s[t - st] : 0;
    __syncthreads();
    s[t] += v;
    __syncthreads();
  }
  const int myoff = bb + s[t] - v0;
  const int node = b * 256 + t;
  if (node < N_NODES) off[node] = myoff;
#pragma unroll
  for (int i = 0; i < 16; ++i) cnt2[t * 16 + i] += myoff;
  __syncthreads();

  // scatter: cnt2 doubles as offset+cursor (atomic return = slot)
  for (int i = t; i < n; i += 256) {
    unsigned p = bbuf[(size_t)b * BCAP + i];
    int srcv = (int)(p >> 8);
    int key = (int)(p & 255u) * 16 + (srcv >> 12);
    int pos = atomicAdd(&cnt2[key], 1);
    esrc[pos] = srcv;
  }
}

// ================= head: pooled means -> linear =================
__device__ inline int lbound(const int* __restrict__ a, int n, int v) {
  int lo = 0, hi = n;
  while (lo < hi) {
    int m = (lo + hi) >> 1;
    if (a[m] < v) lo = m + 1; else hi = m;
  }
  return lo;
}

__global__ __launch_bounds__(128) void k_head(const float* __restrict__ pooled,
    const int* __restrict__ batch, const float* __restrict__ lw,
    const float* __restrict__ lb, float* __restrict__ out) {
  __shared__ float sp[128];
  int g = blockIdx.x;
  int t = threadIdx.x;
  int lo = lbound(batch, N_NODES, g);
  int hi = lbound(batch, N_NODES, g + 1);
  float inv = (hi > lo) ? 1.f / (float)(hi - lo) : 0.f;
  sp[t] = pooled[(size_t)g * OUT_CH + t] * inv;
  __syncthreads();
  if (t < NUM_CLS) {
    float s = lb[t];
#pragma unroll
    for (int k = 0; k < OUT_CH; ++k) s = fmaf(sp[k], lw[k * NUM_CLS + t], s);
    out[g * NUM_CLS + t] = s;
  }
}

extern "C" void kernel_launch(void* const* d_in, const int* in_sizes, int n_in,
                              void* d_out, int out_size, void* d_ws, size_t ws_size,
                              hipStream_t stream) {
  const float* x      = (const float*)d_in[0];
  const int*   ei     = (const int*)d_in[1];
  const int*   batch  = (const int*)d_in[2];
  const float* w1     = (const float*)d_in[4];
  const float* b1     = (const float*)d_in[5];
  const float* rel1w  = (const float*)d_in[6];
  const float* rel1b  = (const float*)d_in[7];
  const float* root1w = (const float*)d_in[8];
  const float* rel2w  = (const float*)d_in[9];
  const float* rel2b  = (const float*)d_in[10];
  const float* root2w = (const float*)d_in[11];
  const float* rel3w  = (const float*)d_in[12];
  const float* rel3b  = (const float*)d_in[13];
  const float* root3w = (const float*)d_in[14];
  const float* linw   = (const float*)d_in[15];
  const float* linb   = (const float*)d_in[16];
  const int* src = ei;
  const int* dst = ei + N_EDGES;
  float* out = (float*)d_out;

  // ---- workspace layout ----
  unsigned short* P = (unsigned short*)d_ws;            // [N,128] bf16
  unsigned short* Q = P + (size_t)N_NODES * 128;        // [N,128] bf16
  unsigned short* R = Q + (size_t)N_NODES * 128;        // [N,128] bf16
  short* WP = (short*)(R + (size_t)N_NODES * 128);
  short* w1p  = WP;                 // 128x64
  short* r1p  = w1p + 8192;         // 64x64
  short* o1p  = r1p + 4096;         // 64x64
  short* r2p  = o1p + 4096;         // 64x128
  short* o2p  = r2p + 8192;         // 64x128
  short* r3p  = o2p + 8192;         // 128x128
  short* o3p  = r3p + 16384;        // 128x128
  int* off     = (int*)(o3p + 16384);                   // N+1
  int* bcnt    = off + (N_NODES + 1);                   // NBUK
  float* pooled = (float*)(bcnt + NBUK);                // [NUM_G * OUT_CH]
  int* esrc    = (int*)(pooled + NUM_G * OUT_CH) + 3;   // [E]
  unsigned* bbuf = (unsigned*)(esrc + N_EDGES);         // [NBUK*BCAP] packed

  PackArgs pk = {w1, rel1w, root1w, rel2w, root2w, rel3w, root3w,
                 w1p, r1p, o1p, r2p, o2p, r3p, o3p};

  // ---- bucketed CSR build + weight pack; stage1 fused into bfin dispatch ----
  hipMemsetAsync(bcnt, 0, NBUK * sizeof(int), stream);
  k_bucketA<<<(N_EDGES + EPB_A - 1) / EPB_A, 256, 0, stream>>>(src, dst, bcnt,
                                                               bbuf, pooled, pk);
  k_bfin_s1<<<NBUK + S1BLK, 256, 0, stream>>>(bcnt, bbuf, off, esrc,
                                              x, w1p, b1, P);

  const int GF = (N_NODES + 15) / 16;     // 3125 blocks, 16 nodes / 1 wave each

  // ---- pipeline ----
  k_fused<64, 64, false><<<GF, 64, 0, stream>>>(P, esrc, off, r1p, o1p, rel1b,
                                                R, batch, pooled);
  k_fused<64, 128, false><<<GF, 64, 0, stream>>>(R, esrc, off, r2p, o2p, rel2b,
                                                 Q, batch, pooled);
  k_fused<128, 128, true><<<GF, 64, 0, stream>>>(Q, esrc, off, r3p, o3p, rel3b,
                                                 P, batch, pooled);
  k_head<<<NUM_G, 128, 0, stream>>>(pooled, batch, linw, linb, out);
}

// Round 15
// 229.020 us; speedup vs baseline: 1.0940x; 1.0090x over previous
//
#include <hip/hip_runtime.h>
#include <hip/hip_bf16.h>

#define N_NODES 50000
#define N_EDGES 800000
#define IN_DIM  128
#define IN_CH   64
#define HIDDEN  64
#define OUT_CH  128
#define NUM_CLS 16
#define NUM_G   512
#define NBUK    ((N_NODES + 255) >> 8)    // 196 buckets of 256 dst nodes
#define BCAP    6144                      // mean 4082/bucket -> huge margin
#define EPB_A   4096                      // edges per pass-A block
#define S1BLK16 196                       // stage1 blocks @16 waves (196*256 >= 50000)

typedef __attribute__((ext_vector_type(8))) short short8;
typedef __attribute__((ext_vector_type(4))) float f32x4;

__device__ inline float bits2f(unsigned short u) {
  unsigned x = (unsigned)u << 16;
  float f;
  __builtin_memcpy(&f, &x, 4);
  return f;
}
__device__ inline unsigned short f2bits(float v) {
  __hip_bfloat16 b = __float2bfloat16(v);   // RNE
  unsigned short s;
  __builtin_memcpy(&s, &b, 2);
  return s;
}
__device__ inline short8 zero8() {
  short8 z;
#pragma unroll
  for (int i = 0; i < 8; ++i) z[i] = 0;
  return z;
}
__device__ inline void acc2(float& a0, float& a1, unsigned v) {
  a0 += bits2f((unsigned short)v);
  a1 += bits2f((unsigned short)(v >> 16));
}
__device__ inline void accu4(float* a, uint4 v) {
  acc2(a[0], a[1], v.x); acc2(a[2], a[3], v.y);
  acc2(a[4], a[5], v.z); acc2(a[6], a[7], v.w);
}

// ============ stage1 body: one wave per 16 rows (R0-proven) ============
__device__ inline void stage1_wave(const float* __restrict__ Ap,
    const short* __restrict__ Wa, const float* __restrict__ bias,
    unsigned short* __restrict__ outp, int rbase, int lane) {
  constexpr int DIN = 128, DOUT = 64, KT = DIN / 32, CT = DOUT / 16;
  const int m = lane & 15;
  const int q = lane >> 4;
  const int row = rbase + m;
  const bool ok = row < N_NODES;

  short8 afr[KT];
#pragma unroll
  for (int kt = 0; kt < KT; ++kt) {
    short8 f = zero8();
    if (ok) {
      const float* ap = Ap + (size_t)row * DIN + kt * 32 + q * 8;
      float4 x0 = *(const float4*)ap;
      float4 x1 = *(const float4*)(ap + 4);
      f[0] = (short)f2bits(x0.x); f[1] = (short)f2bits(x0.y);
      f[2] = (short)f2bits(x0.z); f[3] = (short)f2bits(x0.w);
      f[4] = (short)f2bits(x1.x); f[5] = (short)f2bits(x1.y);
      f[6] = (short)f2bits(x1.z); f[7] = (short)f2bits(x1.w);
    }
    afr[kt] = f;
  }
#pragma unroll
  for (int ct = 0; ct < CT; ++ct) {
    f32x4 c = {0.f, 0.f, 0.f, 0.f};
#pragma unroll
    for (int kt = 0; kt < KT; ++kt) {
      short8 b = *(const short8*)(Wa + ((size_t)(kt * CT + ct) * 64 + lane) * 8);
      c = __builtin_amdgcn_mfma_f32_16x16x32_bf16(afr[kt], b, c, 0, 0, 0);
    }
    float bv = bias[ct * 16 + m];
#pragma unroll
    for (int r = 0; r < 4; ++r) {
      int ro = rbase + q * 4 + r;
      if (ro < N_NODES) outp[(size_t)ro * DOUT + ct * 16 + m] = f2bits(c[r] + bv);
    }
  }
}

// ============ fused gather + dual MFMA, one wave per 16 nodes ============
// Gather loop = FINAL R8/R14/R17-proven form (dead axes: R9 edge-split,
// R10/R15 wider ILP, R12 node perm, R16 K-split, R18 reg lift, R19
// ping-pong; ~435 cyc/edge dependent-chain wall). R21: POOL epilogue pools
// layer 3 in-kernel. R22: smem row stride padded to DOUT+4 (stride 128 == 0
// mod 32 banks gave 4-way write conflicts, 200K/dispatch).
template <int DIN, int DOUT, bool POOL>
__global__ __launch_bounds__(64) void k_fused(
    const unsigned short* __restrict__ h, const int* __restrict__ esrc,
    const int* __restrict__ off, const short* __restrict__ Wa,
    const short* __restrict__ Wh, const float* __restrict__ bias,
    unsigned short* __restrict__ outp, const int* __restrict__ batch,
    float* __restrict__ pooled) {
  constexpr int KT = DIN / 32;
  constexpr int CT = DOUT / 16;
  const int lane = threadIdx.x;
  const int m = lane & 15;
  const int q = lane >> 4;
  const int node = blockIdx.x * 16 + m;  // N_NODES == 16*3125: always valid

  float acc[KT][8];
#pragma unroll
  for (int kt = 0; kt < KT; ++kt)
#pragma unroll
    for (int j = 0; j < 8; ++j) acc[kt][j] = 0.f;

  {
    int e = off[node], end = off[node + 1];
    const unsigned short* hq = h + q * 8;
    for (; e + 2 <= end; e += 2) {
      int s0 = esrc[e], s1 = esrc[e + 1];
      const unsigned short* r0 = hq + (size_t)s0 * DIN;
      const unsigned short* r1 = hq + (size_t)s1 * DIN;
#pragma unroll
      for (int kt = 0; kt < KT; ++kt) {
        uint4 va = *(const uint4*)(r0 + kt * 32);
        uint4 vb = *(const uint4*)(r1 + kt * 32);
        accu4(acc[kt], va);
        accu4(acc[kt], vb);
      }
    }
    if (e < end) {
      const unsigned short* r0 = hq + (size_t)esrc[e] * DIN;
#pragma unroll
      for (int kt = 0; kt < KT; ++kt)
        accu4(acc[kt], *(const uint4*)(r0 + kt * 32));
    }
  }

  short8 afr[KT], hfr[KT];
#pragma unroll
  for (int kt = 0; kt < KT; ++kt) {
    short8 f;
#pragma unroll
    for (int j = 0; j < 8; ++j) f[j] = (short)f2bits(acc[kt][j]);
    afr[kt] = f;
    hfr[kt] = *(const short8*)(h + (size_t)node * DIN + kt * 32 + q * 8);
  }

  const int rbase = blockIdx.x * 16;

  if constexpr (!POOL) {
#pragma unroll
    for (int ct = 0; ct < CT; ++ct) {
      f32x4 c = {0.f, 0.f, 0.f, 0.f};
#pragma unroll
      for (int kt = 0; kt < KT; ++kt) {
        short8 b = *(const short8*)(Wa + ((size_t)(kt * CT + ct) * 64 + lane) * 8);
        c = __builtin_amdgcn_mfma_f32_16x16x32_bf16(afr[kt], b, c, 0, 0, 0);
        short8 bh = *(const short8*)(Wh + ((size_t)(kt * CT + ct) * 64 + lane) * 8);
        c = __builtin_amdgcn_mfma_f32_16x16x32_bf16(hfr[kt], bh, c, 0, 0, 0);
      }
      float bv = bias[ct * 16 + m];
#pragma unroll
      for (int r = 0; r < 4; ++r) {
        int row = rbase + q * 4 + r;
        outp[(size_t)row * DOUT + ct * 16 + m] = f2bits(fmaxf(c[r] + bv, 0.f));
      }
    }
  } else {
    __shared__ float smem[16][DOUT + 4];   // +4: stride 132 = 4 mod 32 banks
    __shared__ int bsm[16];
    if (lane < 16) bsm[lane] = batch[rbase + lane];
#pragma unroll
    for (int ct = 0; ct < CT; ++ct) {
      f32x4 c = {0.f, 0.f, 0.f, 0.f};
#pragma unroll
      for (int kt = 0; kt < KT; ++kt) {
        short8 b = *(const short8*)(Wa + ((size_t)(kt * CT + ct) * 64 + lane) * 8);
        c = __builtin_amdgcn_mfma_f32_16x16x32_bf16(afr[kt], b, c, 0, 0, 0);
        short8 bh = *(const short8*)(Wh + ((size_t)(kt * CT + ct) * 64 + lane) * 8);
        c = __builtin_amdgcn_mfma_f32_16x16x32_bf16(hfr[kt], bh, c, 0, 0, 0);
      }
      float bv = bias[ct * 16 + m];
#pragma unroll
      for (int r = 0; r < 4; ++r) {
        // bf16-round to match the old h3 write exactly, then pool in f32
        smem[q * 4 + r][ct * 16 + m] =
            bits2f(f2bits(fmaxf(c[r] + bv, 0.f)));
      }
    }
    __syncthreads();
    // segment-reduce 16 rows by graph; 2 channels per thread
#pragma unroll
    for (int cc = 0; cc < DOUT / 64; ++cc) {
      const int ch = cc * 64 + lane;
      int g = bsm[0];
      float s = 0.f;
#pragma unroll
      for (int r2 = 0; r2 < 16; ++r2) {
        int gr = bsm[r2];
        if (gr != g) {
          atomicAdd(&pooled[(size_t)g * DOUT + ch], s);
          g = gr;
          s = 0.f;
        }
        s += smem[r2][ch];
      }
      atomicAdd(&pooled[(size_t)g * DOUT + ch], s);
    }
  }
}

// ============ weight pack helper (flat index over all 7 matrices) ============
template <int DIN, int DOUT>
__device__ inline void pack1(const float* __restrict__ W, short* __restrict__ o,
                             int t) {
  constexpr int CT = DOUT / 16;
  int j = t & 7;
  int lane = (t >> 3) & 63;
  int kc = t >> 9;
  int ct = kc % CT;
  int kt = kc / CT;
  int k = kt * 32 + (lane >> 4) * 8 + j;
  int n = ct * 16 + (lane & 15);
  o[t] = (short)f2bits(W[k * DOUT + n]);
}

struct PackArgs {
  const float *w1, *r1, *o1, *r2, *o2, *r3, *o3;
  short *w1p, *r1p, *o1p, *r2p, *o2p, *r3p, *o3p;
};

__device__ inline void packflat(const PackArgs& a, int t) {
  if      (t < 8192)  pack1<128, 64>(a.w1, a.w1p, t);
  else if (t < 12288) pack1<64, 64>(a.r1, a.r1p, t - 8192);
  else if (t < 16384) pack1<64, 64>(a.o1, a.o1p, t - 12288);
  else if (t < 24576) pack1<64, 128>(a.r2, a.r2p, t - 16384);
  else if (t < 32768) pack1<64, 128>(a.o2, a.o2p, t - 24576);
  else if (t < 49152) pack1<128, 128>(a.r3, a.r3p, t - 32768);
  else if (t < 65536) pack1<128, 128>(a.o3, a.o3p, t - 49152);
}

// ================= bucketed CSR build (pass A) + weight pack =================
// R20: per-block LDS counting-sort by bucket before writing bbuf (kills the
// cross-XCD 64B-line write amplification of the old direct scatter).
// R21: also zeroes pooled[] (stream-ordered well before layer 3 uses it).
__global__ __launch_bounds__(256) void k_bucketA(const int* __restrict__ src,
    const int* __restrict__ dst, int* __restrict__ bcnt,
    unsigned* __restrict__ bbuf, float* __restrict__ pooled, PackArgs pk) {
  __shared__ int hist[NBUK], sbase[NBUK], lcur[NBUK], lstart[NBUK];
  __shared__ int sc[256];
  __shared__ unsigned stage[EPB_A];
  __shared__ int s_total;
  const int t = threadIdx.x;

  // fold weight packing + pooled zeroing in (196 blocks x 256 thr)
  {
    int g0 = blockIdx.x * 256 + t;
    packflat(pk, g0);
    packflat(pk, g0 + 50176);
    if (g0 < NUM_G * OUT_CH) pooled[g0] = 0.f;
    int g1 = g0 + 50176;
    if (g1 < NUM_G * OUT_CH) pooled[g1] = 0.f;
  }

  for (int i = t; i < NBUK; i += 256) { hist[i] = 0; lcur[i] = 0; }
  __syncthreads();
  const int e0 = blockIdx.x * EPB_A;
  unsigned p_[16];
  int b_[16];
  int cnt = 0;
#pragma unroll
  for (int k = 0; k < 16; ++k) {
    int e = e0 + k * 256 + t;
    if (e < N_EDGES) {
      int sv = src[e], dv = dst[e];
      int bb = dv >> 8;
      p_[cnt] = ((unsigned)bb << 24) | ((unsigned)sv << 8) | ((unsigned)dv & 255u);
      b_[cnt] = bb;
      atomicAdd(&hist[bb], 1);
      cnt++;
    }
  }
  __syncthreads();
  // global base per bucket (cross-block order arbitrary, as before)
  for (int i = t; i < NBUK; i += 256) sbase[i] = atomicAdd(&bcnt[i], hist[i]);
  // local exclusive scan of hist -> lstart; total edges this block
  int hv = (t < NBUK) ? hist[t] : 0;
  sc[t] = hv;
  __syncthreads();
  for (int st = 1; st < 256; st <<= 1) {
    int v = (t >= st) ? sc[t - st] : 0;
    __syncthreads();
    sc[t] += v;
    __syncthreads();
  }
  if (t < NBUK) lstart[t] = sc[t] - hv;
  if (t == 255) s_total = sc[255];
  __syncthreads();
  // stage entries sorted by bucket (LDS only)
  for (int k = 0; k < cnt; ++k) {
    int bb = b_[k];
    int r = atomicAdd(&lcur[bb], 1);
    stage[lstart[bb] + r] = p_[k];
  }
  __syncthreads();
  // contiguous write-out: consecutive threads hit consecutive sorted slots
  const int total = s_total;
  for (int j = t; j < total; j += 256) {
    unsigned v = stage[j];
    int bb = (int)(v >> 24);
    int gpos = sbase[bb] + (j - lstart[bb]);
    if (gpos < BCAP) bbuf[(size_t)bb * BCAP + gpos] = v & 0x00FFFFFFu;
  }
}

// ===== bfin + stage1 in ONE dispatch; R17 (node, src-band) sort. ======
// R22: 1024-thread blocks. bfin previously ran 196 x 256-thread blocks ->
// ~1 wave/SIMD on most CUs: its global-load + LDS-atomic + scan chains had
// no TLP to hide under. 4 waves/SIMD now. Scans stay 256-wide (t<256 with
// all-thread barriers); count/scatter loops stride 1024. stage1 side: 16
// waves/block, rows guarded.
__global__ __launch_bounds__(1024) void k_bfin_s1(const int* __restrict__ bcnt,
    const unsigned* __restrict__ bbuf, int* __restrict__ off,
    int* __restrict__ esrc,
    const float* __restrict__ x, const short* __restrict__ w1p,
    const float* __restrict__ b1, unsigned short* __restrict__ P) {
  if (blockIdx.x >= NBUK) {
    const int bs = blockIdx.x - NBUK;
    const int wave = threadIdx.x >> 6;
    const int lane = threadIdx.x & 63;
    stage1_wave(x, w1p, b1, P, bs * 256 + wave * 16, lane);
    return;
  }

  __shared__ int cnt2[4096];          // 256 nodes x 16 src-bands (src>>12 <= 12)
  __shared__ int s[256];
  __shared__ int bbase_s;
  const int b = blockIdx.x;
  const int t = threadIdx.x;
  const int nt = 1024;

  for (int i = t; i < 4096; i += nt) cnt2[i] = 0;

  // bucket-base scan, redundantly per block (196 ints; 256-wide, all-thread barriers)
  int bv0 = (t < NBUK) ? min(bcnt[t], BCAP) : 0;
  if (t < 256) s[t] = bv0;
  __syncthreads();
  for (int st = 1; st < 256; st <<= 1) {
    int v = (t >= st && t < 256) ? s[t - st] : 0;
    __syncthreads();
    if (t < 256) s[t] += v;
    __syncthreads();
  }
  if (t == b) bbase_s = s[t] - bv0;                 // exclusive prefix for bucket b
  if (b == 0 && t == NBUK - 1) off[N_NODES] = s[t]; // total edge count
  __syncthreads();
  const int bb = bbase_s;

  // count into (node, band) bins
  const int n = min(bcnt[b], BCAP);
  for (int i = t; i < n; i += nt) {
    unsigned p = bbuf[(size_t)b * BCAP + i];
    int key = (int)(p & 255u) * 16 + (int)((p >> 8) >> 12);
    atomicAdd(&cnt2[key], 1);
  }
  __syncthreads();

  // thread t (<256) owns node t: local scan over its 16 bands (sum = degree)
  int v0 = 0;
  if (t < 256) {
    int run = 0;
#pragma unroll
    for (int i = 0; i < 16; ++i) {
      int tmp = cnt2[t * 16 + i];
      cnt2[t * 16 + i] = run;
      run += tmp;
    }
    v0 = run;
    s[t] = v0;
  }
  __syncthreads();
  for (int st = 1; st < 256; st <<= 1) {
    int v = (t >= st && t < 256) ? s[t - st] : 0;
    __syncthreads();
    if (t < 256) s[t] += v;
    __syncthreads();
  }
  if (t < 256) {
    const int myoff = bb + s[t] - v0;
    const int node = b * 256 + t;
    if (node < N_NODES) off[node] = myoff;
#pragma unroll
    for (int i = 0; i < 16; ++i) cnt2[t * 16 + i] += myoff;
  }
  __syncthreads();

  // scatter: cnt2 doubles as offset+cursor (atomic return = slot)
  for (int i = t; i < n; i += nt) {
    unsigned p = bbuf[(size_t)b * BCAP + i];
    int srcv = (int)(p >> 8);
    int key = (int)(p & 255u) * 16 + (srcv >> 12);
    int pos = atomicAdd(&cnt2[key], 1);
    esrc[pos] = srcv;
  }
}

// ================= head: pooled means -> linear =================
__device__ inline int lbound(const int* __restrict__ a, int n, int v) {
  int lo = 0, hi = n;
  while (lo < hi) {
    int m = (lo + hi) >> 1;
    if (a[m] < v) lo = m + 1; else hi = m;
  }
  return lo;
}

__global__ __launch_bounds__(128) void k_head(const float* __restrict__ pooled,
    const int* __restrict__ batch, const float* __restrict__ lw,
    const float* __restrict__ lb, float* __restrict__ out) {
  __shared__ float sp[128];
  int g = blockIdx.x;
  int t = threadIdx.x;
  int lo = lbound(batch, N_NODES, g);
  int hi = lbound(batch, N_NODES, g + 1);
  float inv = (hi > lo) ? 1.f / (float)(hi - lo) : 0.f;
  sp[t] = pooled[(size_t)g * OUT_CH + t] * inv;
  __syncthreads();
  if (t < NUM_CLS) {
    float s = lb[t];
#pragma unroll
    for (int k = 0; k < OUT_CH; ++k) s = fmaf(sp[k], lw[k * NUM_CLS + t], s);
    out[g * NUM_CLS + t] = s;
  }
}

extern "C" void kernel_launch(void* const* d_in, const int* in_sizes, int n_in,
                              void* d_out, int out_size, void* d_ws, size_t ws_size,
                              hipStream_t stream) {
  const float* x      = (const float*)d_in[0];
  const int*   ei     = (const int*)d_in[1];
  const int*   batch  = (const int*)d_in[2];
  const float* w1     = (const float*)d_in[4];
  const float* b1     = (const float*)d_in[5];
  const float* rel1w  = (const float*)d_in[6];
  const float* rel1b  = (const float*)d_in[7];
  const float* root1w = (const float*)d_in[8];
  const float* rel2w  = (const float*)d_in[9];
  const float* rel2b  = (const float*)d_in[10];
  const float* root2w = (const float*)d_in[11];
  const float* rel3w  = (const float*)d_in[12];
  const float* rel3b  = (const float*)d_in[13];
  const float* root3w = (const float*)d_in[14];
  const float* linw   = (const float*)d_in[15];
  const float* linb   = (const float*)d_in[16];
  const int* src = ei;
  const int* dst = ei + N_EDGES;
  float* out = (float*)d_out;

  // ---- workspace layout ----
  unsigned short* P = (unsigned short*)d_ws;            // [N,128] bf16
  unsigned short* Q = P + (size_t)N_NODES * 128;        // [N,128] bf16
  unsigned short* R = Q + (size_t)N_NODES * 128;        // [N,128] bf16
  short* WP = (short*)(R + (size_t)N_NODES * 128);
  short* w1p  = WP;                 // 128x64
  short* r1p  = w1p + 8192;         // 64x64
  short* o1p  = r1p + 4096;         // 64x64
  short* r2p  = o1p + 4096;         // 64x128
  short* o2p  = r2p + 8192;         // 64x128
  short* r3p  = o2p + 8192;         // 128x128
  short* o3p  = r3p + 16384;        // 128x128
  int* off     = (int*)(o3p + 16384);                   // N+1
  int* bcnt    = off + (N_NODES + 1);                   // NBUK
  float* pooled = (float*)(bcnt + NBUK);                // [NUM_G * OUT_CH]
  int* esrc    = (int*)(pooled + NUM_G * OUT_CH) + 3;   // [E]
  unsigned* bbuf = (unsigned*)(esrc + N_EDGES);         // [NBUK*BCAP] packed

  PackArgs pk = {w1, rel1w, root1w, rel2w, root2w, rel3w, root3w,
                 w1p, r1p, o1p, r2p, o2p, r3p, o3p};

  // ---- bucketed CSR build + weight pack; stage1 fused into bfin dispatch ----
  hipMemsetAsync(bcnt, 0, NBUK * sizeof(int), stream);
  k_bucketA<<<(N_EDGES + EPB_A - 1) / EPB_A, 256, 0, stream>>>(src, dst, bcnt,
                                                               bbuf, pooled, pk);
  k_bfin_s1<<<NBUK + S1BLK16, 1024, 0, stream>>>(bcnt, bbuf, off, esrc,
                                                 x, w1p, b1, P);

  const int GF = (N_NODES + 15) / 16;     // 3125 blocks, 16 nodes / 1 wave each

  // ---- pipeline ----
  k_fused<64, 64, false><<<GF, 64, 0, stream>>>(P, esrc, off, r1p, o1p, rel1b,
                                                R, batch, pooled);
  k_fused<64, 128, false><<<GF, 64, 0, stream>>>(R, esrc, off, r2p, o2p, rel2b,
                                                 Q, batch, pooled);
  k_fused<128, 128, true><<<GF, 64, 0, stream>>>(Q, esrc, off, r3p, o3p, rel3b,
                                                 P, batch, pooled);
  k_head<<<NUM_G, 128, 0, stream>>>(pooled, batch, linw, linb, out);
}